// Round 12
// baseline (41.533 us; speedup 1.0000x reference)
//
#include <hip/hip_runtime.h>
#include <math.h>

#define N_NODES 30000
#define K_NBR   16
#define C_IN    256
#define C_OUT   128
#define KS      9
#define S_MB    17
#define BR      32
#define NT      938            // ceil(30000/32); 469 blocks x 2 tiles exactly

typedef __attribute__((ext_vector_type(4))) float f32x4;
typedef __attribute__((ext_vector_type(2))) float f32x2;
typedef __attribute__((ext_vector_type(8))) short bf16x8;

static __device__ __forceinline__ ushort f2bf(float f) {
    uint u = __builtin_bit_cast(uint, f);
    u += 0x7fffu + ((u >> 16) & 1u);          // round-to-nearest-even
    return (ushort)(u >> 16);
}

// ---------------------------------------------------------------------------
// Prep: blocks 0..31 convert stacked W (rows 0..127 = W_lin, 128..255 = W_res)
// into fragment-ordered bf16 Bf. Block 32 computes per-channel Ws/Cd.
// ---------------------------------------------------------------------------
__global__ __launch_bounds__(256)
void pcg_prep(const float* __restrict__ W_lin,
              const float* __restrict__ W_res,
              const float* __restrict__ weight,
              const float* __restrict__ b_lin,
              const float* __restrict__ bias,
              const float* __restrict__ b_res,
              ushort* __restrict__ Bf,
              float* __restrict__ Ws,
              float* __restrict__ Cd) {
    if (blockIdx.x == 32) {
        int d = threadIdx.x;
        if (d >= C_OUT) return;
        float freq = powf(10000.0f, -(float)(d & ~1) / (float)C_OUT);
        float ws = 0.f, p = 0.f;
        for (int s = 0; s < S_MB; ++s) {
            int idx = (int)floorf((float)s * (9.0f / 17.0f));
            ws += weight[d * KS + idx];
            float ang = (float)idx * freq;
            p += (d & 1) ? cosf(ang) : sinf(ang);
        }
        Ws[d] = ws;
        Cd[d] = ws * ((float)(K_NBR + 1) * b_lin[d] + p) + bias[d] + b_res[d];
        return;
    }
    const int tt     = blockIdx.x * 256 + threadIdx.x;   // 0..8191
    const int col_lo = tt & 15;
    const int ksub   = (tt >> 4) & 3;
    const int colhi  = (tt >> 6) & 15;
    const int kc     = tt >> 10;
    const int col    = colhi * 16 + col_lo;
    const int k0     = kc * 32 + ksub * 8;
    const float* Wr = (col < C_OUT)
        ? &W_lin[(size_t)col * C_IN + k0]
        : &W_res[(size_t)(col - C_OUT) * C_IN + k0];
    const f32x4 w0 = *reinterpret_cast<const f32x4*>(Wr);
    const f32x4 w1 = *reinterpret_cast<const f32x4*>(Wr + 4);
    ushort b[8] = { f2bf(w0.x), f2bf(w0.y), f2bf(w0.z), f2bf(w0.w),
                    f2bf(w1.x), f2bf(w1.y), f2bf(w1.z), f2bf(w1.w) };
    *reinterpret_cast<uint4*>(&Bf[(size_t)tt * 8]) =
        *reinterpret_cast<const uint4*>(b);
}

// ---------------------------------------------------------------------------
// MFMA GEMM + epilogue fold — double-buffered 2-tile pipeline (T14 split):
//   tile t+1's global loads issue into REGISTERS before tile t's compute
//   (HBM latency hides under MFMA/ds_read), convert+ds_write after.
// Block: 512 threads = 8 waves; per tile BR=32 rows x 256 stacked cols.
// Wave w owns G colhi w and R colhi 8+w (same d) -> in-register fold.
// All LDS buffer indices compile-time constant. Swizzle conflict-free (R7).
// ---------------------------------------------------------------------------
__global__ __launch_bounds__(512, 4)
void pcg_mfma(const float* __restrict__ ndata,
              const ushort* __restrict__ Bf,
              const float* __restrict__ Ws,
              const float* __restrict__ Cd,
              ushort* __restrict__ Gs,
              ushort* __restrict__ Pc) {
    __shared__ short sA0[8192];                // buffer 0: 16 KB
    __shared__ short sA1[8192];                // buffer 1: 16 KB

    const int t    = threadIdx.x;
    const int wave = t >> 6;                   // 0..7
    const int l    = t & 63;
    const int bu   = l ^ (l >> 4);
    const int chG  = wave;
    const int chR  = 8 + wave;
    const int c    = wave * 16 + (l & 15);     // output channel d
    const int rl   = (l >> 4) * 4;
    const float wsc = Ws[c];
    const float cdc = Cd[c];

    const int tile0 = blockIdx.x * 2;          // tiles tile0, tile0+1 (<938)

    // staging geometry for this thread (2 iters x 2 f32x4 = 32B/iter)
    const int row0 = t >> 5;                   // iter 0: rows 0..15
    const int row1 = (512 + t) >> 5;           // iter 1: rows 16..31
    const int kch  = t & 31;
    const int kc0  = kch >> 2, ks0 = kch & 3;
    // LDS target (same for both tiles; buffer differs)
    const int f0   = kc0 * 2 + (row0 >> 4);
    const int up0  = (((row0 & 15) | (ks0 << 4)) ^ ks0) ^ ((kc0 & 1) << 2);
    const int f1   = kc0 * 2 + (row1 >> 4);
    const int up1  = (((row1 & 15) | (ks0 << 4)) ^ ks0) ^ ((kc0 & 1) << 2);

#define STAGE_LOAD(TILE, R0A, R0B, R1A, R1B)                                   \
    {                                                                          \
        const int n0_ = (TILE) * BR;                                           \
        R0A = (f32x4){0.f,0.f,0.f,0.f}; R0B = R0A; R1A = R0A; R1B = R0A;       \
        if (n0_ + row0 < N_NODES) {                                            \
            const float* p_ = &ndata[(size_t)(n0_ + row0) * C_IN + kch * 8];   \
            R0A = *reinterpret_cast<const f32x4*>(p_);                         \
            R0B = *reinterpret_cast<const f32x4*>(p_ + 4);                     \
        }                                                                      \
        if (n0_ + row1 < N_NODES) {                                            \
            const float* p_ = &ndata[(size_t)(n0_ + row1) * C_IN + kch * 8];   \
            R1A = *reinterpret_cast<const f32x4*>(p_);                         \
            R1B = *reinterpret_cast<const f32x4*>(p_ + 4);                     \
        }                                                                      \
    }

#define STAGE_WRITE(SBUF, R0A, R0B, R1A, R1B)                                  \
    {                                                                          \
        uint4 w_;                                                              \
        w_.x = (uint)f2bf(R0A.x) | ((uint)f2bf(R0A.y) << 16);                  \
        w_.y = (uint)f2bf(R0A.z) | ((uint)f2bf(R0A.w) << 16);                  \
        w_.z = (uint)f2bf(R0B.x) | ((uint)f2bf(R0B.y) << 16);                  \
        w_.w = (uint)f2bf(R0B.z) | ((uint)f2bf(R0B.w) << 16);                  \
        *reinterpret_cast<uint4*>(&SBUF[f0 * 512 + up0 * 8]) = w_;             \
        w_.x = (uint)f2bf(R1A.x) | ((uint)f2bf(R1A.y) << 16);                  \
        w_.y = (uint)f2bf(R1A.z) | ((uint)f2bf(R1A.w) << 16);                  \
        w_.z = (uint)f2bf(R1B.x) | ((uint)f2bf(R1B.y) << 16);                  \
        w_.w = (uint)f2bf(R1B.z) | ((uint)f2bf(R1B.w) << 16);                  \
        *reinterpret_cast<uint4*>(&SBUF[f1 * 512 + up1 * 8]) = w_;             \
    }

#define COMPUTE_STORE(SBUF, TILE)                                              \
    {                                                                          \
        const int n0_ = (TILE) * BR;                                           \
        f32x4 accG0 = {}, accG1 = {}, accR0 = {}, accR1 = {};                  \
        _Pragma("unroll")                                                      \
        for (int kc = 0; kc < 8; ++kc) {                                       \
            const int ux = bu ^ ((kc & 1) << 2);                               \
            const bf16x8 a0 = *reinterpret_cast<const bf16x8*>(                \
                &SBUF[(kc * 2 + 0) * 512 + ux * 8]);                           \
            const bf16x8 a1 = *reinterpret_cast<const bf16x8*>(                \
                &SBUF[(kc * 2 + 1) * 512 + ux * 8]);                           \
            const bf16x8 bG = *reinterpret_cast<const bf16x8*>(                \
                &Bf[((size_t)(kc * 16 + chG) * 64 + l) * 8]);                  \
            const bf16x8 bR = *reinterpret_cast<const bf16x8*>(                \
                &Bf[((size_t)(kc * 16 + chR) * 64 + l) * 8]);                  \
            accG0 = __builtin_amdgcn_mfma_f32_16x16x32_bf16(a0, bG, accG0, 0, 0, 0); \
            accR0 = __builtin_amdgcn_mfma_f32_16x16x32_bf16(a0, bR, accR0, 0, 0, 0); \
            accG1 = __builtin_amdgcn_mfma_f32_16x16x32_bf16(a1, bG, accG1, 0, 0, 0); \
            accR1 = __builtin_amdgcn_mfma_f32_16x16x32_bf16(a1, bR, accR1, 0, 0, 0); \
        }                                                                      \
        _Pragma("unroll")                                                      \
        for (int j = 0; j < 4; ++j) {                                          \
            const int r0_ = n0_ + rl + j;                                      \
            if (r0_ < N_NODES) {                                               \
                const float g_ = wsc * accG0[j];                               \
                Gs[(size_t)r0_ * C_OUT + c] = f2bf(g_);                        \
                Pc[(size_t)r0_ * C_OUT + c] = f2bf(g_ + accR0[j] + cdc);       \
            }                                                                  \
            const int r1_ = n0_ + 16 + rl + j;                                 \
            if (r1_ < N_NODES) {                                               \
                const float g_ = wsc * accG1[j];                               \
                Gs[(size_t)r1_ * C_OUT + c] = f2bf(g_);                        \
                Pc[(size_t)r1_ * C_OUT + c] = f2bf(g_ + accR1[j] + cdc);       \
            }                                                                  \
        }                                                                      \
    }

    f32x4 r0a, r0b, r1a, r1b;
    // prologue: tile0 -> buf0
    STAGE_LOAD(tile0, r0a, r0b, r1a, r1b);
    STAGE_WRITE(sA0, r0a, r0b, r1a, r1b);
    __syncthreads();

    // pipeline: issue tile1 loads, compute tile0, write tile1, compute tile1
    STAGE_LOAD(tile0 + 1, r0a, r0b, r1a, r1b);
    COMPUTE_STORE(sA0, tile0);
    STAGE_WRITE(sA1, r0a, r0b, r1a, r1b);
    __syncthreads();
    COMPUTE_STORE(sA1, tile0 + 1);

#undef STAGE_LOAD
#undef STAGE_WRITE
#undef COMPUTE_STORE
}

// ---------------------------------------------------------------------------
// Gather: out[n][d] = Pc[n][d] + sum_k Gs[neighbors[n,k]][d]
// (R7 measured ~2.7 us — at its cache/write floor, unchanged)
// ---------------------------------------------------------------------------
__global__ __launch_bounds__(256)
void pcg_gather(const int* __restrict__ neighbors,
                const ushort* __restrict__ Gs,
                const ushort* __restrict__ Pc,
                float* __restrict__ out) {
    __shared__ int snb[64];
    const int t = threadIdx.x;
    if (t < 64) snb[t] = neighbors[(size_t)blockIdx.x * 64 + t];
    __syncthreads();

    const int g = t >> 6;                      // node group 0..3
    const int l = t & 63;
    const int n = blockIdx.x * 4 + g;

    uint p = *reinterpret_cast<const uint*>(&Pc[(size_t)n * C_OUT + 2 * l]);
    float a0 = __builtin_bit_cast(float, p << 16);
    float a1 = __builtin_bit_cast(float, p & 0xffff0000u);

#pragma unroll
    for (int k = 0; k < K_NBR; ++k) {
        const int m = snb[g * 16 + k];
        uint v = *reinterpret_cast<const uint*>(&Gs[(size_t)m * C_OUT + 2 * l]);
        a0 += __builtin_bit_cast(float, v << 16);
        a1 += __builtin_bit_cast(float, v & 0xffff0000u);
    }

    f32x2 o = {a0, a1};
    *reinterpret_cast<f32x2*>(&out[(size_t)n * C_OUT + 2 * l]) = o;
}

// ---------------------------------------------------------------------------
extern "C" void kernel_launch(void* const* d_in, const int* in_sizes, int n_in,
                              void* d_out, int out_size, void* d_ws, size_t ws_size,
                              hipStream_t stream) {
    const float* ndata     = (const float*)d_in[0];
    const int*   neighbors = (const int*)  d_in[1];
    const float* W_lin     = (const float*)d_in[2];
    const float* b_lin     = (const float*)d_in[3];
    const float* weight    = (const float*)d_in[4];
    const float* bias      = (const float*)d_in[5];
    const float* W_res     = (const float*)d_in[6];
    const float* b_res     = (const float*)d_in[7];
    float* out = (float*)d_out;

    ushort* Bf = (ushort*)d_ws;                          // [8192][8] = 128 KB
    ushort* Gq = Bf + 65536;                             // Gs [N][128] = 7.68 MB
    ushort* Pq = Gq + (size_t)N_NODES * C_OUT;           // Pc [N][128] = 7.68 MB
    float*  Ws = (float*)(Pq + (size_t)N_NODES * C_OUT); // [128]
    float*  Cd = Ws + C_OUT;                             // [128]

    pcg_prep<<<33, 256, 0, stream>>>(W_lin, W_res, weight, b_lin, bias, b_res,
                                     Bf, Ws, Cd);
    pcg_mfma<<<NT / 2, 512, 0, stream>>>(ndata, Bf, Ws, Cd, Gq, Pq);
    pcg_gather<<<N_NODES / 4, 256, 0, stream>>>(neighbors, Gq, Pq, out);
}